// Round 1
// baseline (508.767 us; speedup 1.0000x reference)
//
#include <hip/hip_runtime.h>

#define IN_CH 128
#define HID_CH 128
#define OUT_CH 64

// ---------------------------------------------------------------------------
// CSR build: degree count -> exclusive scan -> bucket fill
// ---------------------------------------------------------------------------

__global__ void count_deg_kernel(const int* __restrict__ ei, int* __restrict__ deg,
                                 int n_edges) {
    int e = blockIdx.x * blockDim.x + threadIdx.x;
    if (e < n_edges) {
        atomicAdd(&deg[ei[n_edges + e]], 1);  // row 1 = dst
    }
}

__global__ __launch_bounds__(1024) void scan_kernel(const int* __restrict__ deg,
                                                    int* __restrict__ offsets,
                                                    int* __restrict__ cursor,
                                                    int n) {
    __shared__ int part[1024];
    int tid = threadIdx.x;
    int chunk = (n + 1023) / 1024;
    int start = tid * chunk;
    int end   = min(start + chunk, n);
    int s = 0;
    for (int i = start; i < end; ++i) s += deg[i];
    part[tid] = s;
    __syncthreads();
    // Hillis-Steele inclusive scan over 1024 partials
    for (int off = 1; off < 1024; off <<= 1) {
        int v = (tid >= off) ? part[tid - off] : 0;
        __syncthreads();
        part[tid] += v;
        __syncthreads();
    }
    int run = part[tid] - s;  // exclusive base for this thread's chunk
    for (int i = start; i < end; ++i) {
        offsets[i] = run;
        cursor[i]  = run;
        run += deg[i];
    }
    if (tid == 1023) offsets[n] = part[1023];
}

__global__ void fill_kernel(const int* __restrict__ ei, int* __restrict__ cursor,
                            int* __restrict__ edge_src, int n_edges) {
    int e = blockIdx.x * blockDim.x + threadIdx.x;
    if (e < n_edges) {
        int s = ei[e];                 // row 0 = src
        int d = ei[n_edges + e];       // row 1 = dst
        int pos = atomicAdd(&cursor[d], 1);
        edge_src[pos] = s;
    }
}

// ---------------------------------------------------------------------------
// Gather-side mean: one wave (64 lanes) per destination node, 128 channels.
// Each lane owns channels {lane, lane+64}; every edge read is a coalesced
// 512B row. No fp32 atomics anywhere.
// ---------------------------------------------------------------------------

__global__ __launch_bounds__(256) void gather_mean_kernel(
    const float* __restrict__ feat, const int* __restrict__ offsets,
    const int* __restrict__ edge_src, float* __restrict__ mean, int n_nodes) {
    int wid  = (blockIdx.x * blockDim.x + threadIdx.x) >> 6;
    int lane = threadIdx.x & 63;
    if (wid >= n_nodes) return;
    int beg = offsets[wid];
    int end = offsets[wid + 1];
    float s0 = 0.f, s1 = 0.f;
    for (int e = beg; e < end; ++e) {
        const float* row = feat + (size_t)edge_src[e] * 128;
        s0 += row[lane];
        s1 += row[lane + 64];
    }
    float inv = 1.0f / fmaxf((float)(end - beg), 1.0f);
    mean[(size_t)wid * 128 + lane]      = s0 * inv;
    mean[(size_t)wid * 128 + lane + 64] = s1 * inv;
}

// ---------------------------------------------------------------------------
// Layer 1: h = relu(mean @ W1l + x @ W1r + b1)      [50k,128]x[128,128]
// 32-node tile in LDS; thread computes 4 nodes x 4 cols.
// ---------------------------------------------------------------------------

__global__ __launch_bounds__(256) void l1_kernel(
    const float* __restrict__ mean, const float* __restrict__ x,
    const float* __restrict__ Wl, const float* __restrict__ Wr,
    const float* __restrict__ b, float* __restrict__ h, int n_nodes) {
    __shared__ float sM[32][128];
    __shared__ float sX[32][128];
    int tid = threadIdx.x;
    int node0 = blockIdx.x * 32;

    for (int i = tid; i < 32 * 32; i += 256) {  // 1024 float4 loads per array
        int r = i >> 5;
        int c = (i & 31) << 2;
        int g = node0 + r;
        float4 mv = make_float4(0, 0, 0, 0), xv = make_float4(0, 0, 0, 0);
        if (g < n_nodes) {
            mv = *(const float4*)(mean + (size_t)g * 128 + c);
            xv = *(const float4*)(x + (size_t)g * 128 + c);
        }
        *(float4*)&sM[r][c] = mv;
        *(float4*)&sX[r][c] = xv;
    }
    __syncthreads();

    int cg = tid & 31, ng = tid >> 5;
    int c0 = cg << 2, nb = ng << 2;
    float acc[4][4];
    float4 bb = *(const float4*)(b + c0);
#pragma unroll
    for (int n = 0; n < 4; ++n) {
        acc[n][0] = bb.x; acc[n][1] = bb.y; acc[n][2] = bb.z; acc[n][3] = bb.w;
    }

    for (int k = 0; k < 128; k += 4) {
        float4 a4[4], x4[4];
#pragma unroll
        for (int n = 0; n < 4; ++n) {
            a4[n] = *(const float4*)&sM[nb + n][k];
            x4[n] = *(const float4*)&sX[nb + n][k];
        }
#pragma unroll
        for (int kk = 0; kk < 4; ++kk) {
            float4 wl = *(const float4*)(Wl + (k + kk) * 128 + c0);
            float4 wr = *(const float4*)(Wr + (k + kk) * 128 + c0);
#pragma unroll
            for (int n = 0; n < 4; ++n) {
                float a  = ((const float*)&a4[n])[kk];
                float xx = ((const float*)&x4[n])[kk];
                acc[n][0] += a * wl.x + xx * wr.x;
                acc[n][1] += a * wl.y + xx * wr.y;
                acc[n][2] += a * wl.z + xx * wr.z;
                acc[n][3] += a * wl.w + xx * wr.w;
            }
        }
    }

#pragma unroll
    for (int n = 0; n < 4; ++n) {
        int g = node0 + nb + n;
        if (g < n_nodes) {
            float4 o;
            o.x = fmaxf(acc[n][0], 0.f);
            o.y = fmaxf(acc[n][1], 0.f);
            o.z = fmaxf(acc[n][2], 0.f);
            o.w = fmaxf(acc[n][3], 0.f);
            *(float4*)(h + (size_t)g * 128 + c0) = o;
        }
    }
}

// ---------------------------------------------------------------------------
// Layer 2: out = mean2 @ W2l + h @ W2r + b2         [50k,128]x[128,64]
// 32-node tile; thread computes 2 nodes x 4 cols.
// ---------------------------------------------------------------------------

__global__ __launch_bounds__(256) void l2_kernel(
    const float* __restrict__ mean, const float* __restrict__ hfeat,
    const float* __restrict__ Wl, const float* __restrict__ Wr,
    const float* __restrict__ b, float* __restrict__ out, int n_nodes) {
    __shared__ float sM[32][128];
    __shared__ float sH[32][128];
    int tid = threadIdx.x;
    int node0 = blockIdx.x * 32;

    for (int i = tid; i < 32 * 32; i += 256) {
        int r = i >> 5;
        int c = (i & 31) << 2;
        int g = node0 + r;
        float4 mv = make_float4(0, 0, 0, 0), hv = make_float4(0, 0, 0, 0);
        if (g < n_nodes) {
            mv = *(const float4*)(mean + (size_t)g * 128 + c);
            hv = *(const float4*)(hfeat + (size_t)g * 128 + c);
        }
        *(float4*)&sM[r][c] = mv;
        *(float4*)&sH[r][c] = hv;
    }
    __syncthreads();

    int cg = tid & 15, ng = tid >> 4;
    int c0 = cg << 2, nb = ng << 1;
    float acc[2][4];
    float4 bb = *(const float4*)(b + c0);
#pragma unroll
    for (int n = 0; n < 2; ++n) {
        acc[n][0] = bb.x; acc[n][1] = bb.y; acc[n][2] = bb.z; acc[n][3] = bb.w;
    }

    for (int k = 0; k < 128; k += 4) {
        float4 a4[2], h4[2];
#pragma unroll
        for (int n = 0; n < 2; ++n) {
            a4[n] = *(const float4*)&sM[nb + n][k];
            h4[n] = *(const float4*)&sH[nb + n][k];
        }
#pragma unroll
        for (int kk = 0; kk < 4; ++kk) {
            float4 wl = *(const float4*)(Wl + (k + kk) * 64 + c0);
            float4 wr = *(const float4*)(Wr + (k + kk) * 64 + c0);
#pragma unroll
            for (int n = 0; n < 2; ++n) {
                float a  = ((const float*)&a4[n])[kk];
                float hh = ((const float*)&h4[n])[kk];
                acc[n][0] += a * wl.x + hh * wr.x;
                acc[n][1] += a * wl.y + hh * wr.y;
                acc[n][2] += a * wl.z + hh * wr.z;
                acc[n][3] += a * wl.w + hh * wr.w;
            }
        }
    }

#pragma unroll
    for (int n = 0; n < 2; ++n) {
        int g = node0 + nb + n;
        if (g < n_nodes) {
            float4 o;
            o.x = acc[n][0]; o.y = acc[n][1]; o.z = acc[n][2]; o.w = acc[n][3];
            *(float4*)(out + (size_t)g * 64 + c0) = o;
        }
    }
}

// ---------------------------------------------------------------------------

extern "C" void kernel_launch(void* const* d_in, const int* in_sizes, int n_in,
                              void* d_out, int out_size, void* d_ws, size_t ws_size,
                              hipStream_t stream) {
    const float* x   = (const float*)d_in[0];
    const int*   ei  = (const int*)d_in[1];
    const float* W1l = (const float*)d_in[2];
    const float* W1r = (const float*)d_in[3];
    const float* b1  = (const float*)d_in[4];
    const float* W2l = (const float*)d_in[5];
    const float* W2r = (const float*)d_in[6];
    const float* b2  = (const float*)d_in[7];
    float* out = (float*)d_out;

    int n_nodes = in_sizes[0] / IN_CH;
    int n_edges = in_sizes[1] / 2;

    // Workspace layout (all re-poisoned every call; everything written before read)
    char* ws = (char*)d_ws;
    int* deg      = (int*)ws;                    // n_nodes
    int* offsets  = deg + n_nodes;               // n_nodes + 1
    int* cursor   = offsets + n_nodes + 1;       // n_nodes
    int* edge_src = cursor + n_nodes;            // n_edges
    size_t off = ((size_t)(3 * n_nodes + 1 + n_edges)) * sizeof(int);
    off = (off + 255) & ~(size_t)255;            // 256B align for float4
    float* mean = (float*)(ws + off);            // n_nodes * 128 (reused for both layers)
    float* h    = mean + (size_t)n_nodes * HID_CH;  // n_nodes * 128

    hipMemsetAsync(deg, 0, n_nodes * sizeof(int), stream);

    const int TB = 256;
    int eblocks = (n_edges + TB - 1) / TB;
    count_deg_kernel<<<eblocks, TB, 0, stream>>>(ei, deg, n_edges);
    scan_kernel<<<1, 1024, 0, stream>>>(deg, offsets, cursor, n_nodes);
    fill_kernel<<<eblocks, TB, 0, stream>>>(ei, cursor, edge_src, n_edges);

    int gblocks = (n_nodes * 64 + TB - 1) / TB;  // one wave per node
    int mblocks = (n_nodes + 31) / 32;

    // Layer 1
    gather_mean_kernel<<<gblocks, TB, 0, stream>>>(x, offsets, edge_src, mean, n_nodes);
    l1_kernel<<<mblocks, 256, 0, stream>>>(mean, x, W1l, W1r, b1, h, n_nodes);

    // Layer 2 (reuse CSR and mean buffer)
    gather_mean_kernel<<<gblocks, TB, 0, stream>>>(h, offsets, edge_src, mean, n_nodes);
    l2_kernel<<<mblocks, 256, 0, stream>>>(mean, h, W2l, W2r, b2, out, n_nodes);
}

// Round 2
// 382.954 us; speedup vs baseline: 1.3285x; 1.3285x over previous
//
#include <hip/hip_runtime.h>

#define IN_CH 128
#define HID_CH 128
#define OUT_CH 64
#define SCAN_B 256

// ---------------------------------------------------------------------------
// CSR build: degree count -> 3-phase multi-block exclusive scan -> bucket fill
// ---------------------------------------------------------------------------

__global__ void count_deg_kernel(const int* __restrict__ ei, int* __restrict__ deg,
                                 int n_edges) {
    int e = blockIdx.x * blockDim.x + threadIdx.x;
    if (e < n_edges) {
        atomicAdd(&deg[ei[n_edges + e]], 1);  // row 1 = dst
    }
}

// Phase A: per-block sums of deg
__global__ __launch_bounds__(SCAN_B) void scan_partials_kernel(
    const int* __restrict__ deg, int* __restrict__ partials, int n) {
    __shared__ int ws[SCAN_B / 64];
    int i = blockIdx.x * SCAN_B + threadIdx.x;
    int v = (i < n) ? deg[i] : 0;
    // wave reduce
    for (int off = 32; off > 0; off >>= 1) v += __shfl_down(v, off, 64);
    int lane = threadIdx.x & 63, w = threadIdx.x >> 6;
    if (lane == 0) ws[w] = v;
    __syncthreads();
    if (threadIdx.x == 0) {
        int s = 0;
        for (int k = 0; k < SCAN_B / 64; ++k) s += ws[k];
        partials[blockIdx.x] = s;
    }
}

// Phase B: single small block scans the partials (<=1024 blocks' worth)
__global__ __launch_bounds__(1024) void scan_bases_kernel(
    const int* __restrict__ partials, int* __restrict__ bases,
    int* __restrict__ offsets, int nblocks, int n) {
    __shared__ int sm[1024];
    int t = threadIdx.x;
    int v = (t < nblocks) ? partials[t] : 0;
    sm[t] = v;
    __syncthreads();
    for (int off = 1; off < 1024; off <<= 1) {
        int u = (t >= off) ? sm[t - off] : 0;
        __syncthreads();
        sm[t] += u;
        __syncthreads();
    }
    if (t < nblocks) bases[t] = sm[t] - v;   // exclusive base per block
    if (t == 1023) offsets[n] = sm[1023];    // total edge count
}

// Phase C: block-local exclusive scan + base add -> offsets & cursor
__global__ __launch_bounds__(SCAN_B) void scan_final_kernel(
    const int* __restrict__ deg, const int* __restrict__ bases,
    int* __restrict__ offsets, int* __restrict__ cursor, int n) {
    __shared__ int sm[SCAN_B];
    int t = threadIdx.x;
    int i = blockIdx.x * SCAN_B + t;
    int v = (i < n) ? deg[i] : 0;
    sm[t] = v;
    __syncthreads();
    for (int off = 1; off < SCAN_B; off <<= 1) {
        int u = (t >= off) ? sm[t - off] : 0;
        __syncthreads();
        sm[t] += u;
        __syncthreads();
    }
    if (i < n) {
        int o = bases[blockIdx.x] + sm[t] - v;
        offsets[i] = o;
        cursor[i]  = o;
    }
}

__global__ void fill_kernel(const int* __restrict__ ei, int* __restrict__ cursor,
                            int* __restrict__ edge_src, int n_edges) {
    int e = blockIdx.x * blockDim.x + threadIdx.x;
    if (e < n_edges) {
        int s = ei[e];                 // row 0 = src
        int d = ei[n_edges + e];       // row 1 = dst
        int pos = atomicAdd(&cursor[d], 1);
        edge_src[pos] = s;
    }
}

// ---------------------------------------------------------------------------
// Gather-side mean: one wave per destination node; lane reads float2 so a
// whole 512B feature row is one coalesced transaction. 2-edge unroll for MLP.
// ---------------------------------------------------------------------------

__global__ __launch_bounds__(256) void gather_mean_kernel(
    const float* __restrict__ feat, const int* __restrict__ offsets,
    const int* __restrict__ edge_src, float* __restrict__ mean, int n_nodes) {
    int wid  = (blockIdx.x * blockDim.x + threadIdx.x) >> 6;
    int lane = threadIdx.x & 63;
    if (wid >= n_nodes) return;
    int beg = offsets[wid];
    int end = offsets[wid + 1];
    float sx = 0.f, sy = 0.f;
    int e = beg;
    for (; e + 1 < end; e += 2) {
        float2 a = *(const float2*)(feat + (size_t)edge_src[e]     * 128 + 2 * lane);
        float2 c = *(const float2*)(feat + (size_t)edge_src[e + 1] * 128 + 2 * lane);
        sx += a.x + c.x;
        sy += a.y + c.y;
    }
    if (e < end) {
        float2 a = *(const float2*)(feat + (size_t)edge_src[e] * 128 + 2 * lane);
        sx += a.x;
        sy += a.y;
    }
    float inv = 1.0f / fmaxf((float)(end - beg), 1.0f);
    float2 o;
    o.x = sx * inv;
    o.y = sy * inv;
    *(float2*)(mean + (size_t)wid * 128 + 2 * lane) = o;
}

// ---------------------------------------------------------------------------
// Layer 1: h = relu(mean @ W1l + x @ W1r + b1)      [50k,128]x[128,128]
// ---------------------------------------------------------------------------

__global__ __launch_bounds__(256) void l1_kernel(
    const float* __restrict__ mean, const float* __restrict__ x,
    const float* __restrict__ Wl, const float* __restrict__ Wr,
    const float* __restrict__ b, float* __restrict__ h, int n_nodes) {
    __shared__ float sM[32][128];
    __shared__ float sX[32][128];
    int tid = threadIdx.x;
    int node0 = blockIdx.x * 32;

    for (int i = tid; i < 32 * 32; i += 256) {
        int r = i >> 5;
        int c = (i & 31) << 2;
        int g = node0 + r;
        float4 mv = make_float4(0, 0, 0, 0), xv = make_float4(0, 0, 0, 0);
        if (g < n_nodes) {
            mv = *(const float4*)(mean + (size_t)g * 128 + c);
            xv = *(const float4*)(x + (size_t)g * 128 + c);
        }
        *(float4*)&sM[r][c] = mv;
        *(float4*)&sX[r][c] = xv;
    }
    __syncthreads();

    int cg = tid & 31, ng = tid >> 5;
    int c0 = cg << 2, nb = ng << 2;
    float acc[4][4];
    float4 bb = *(const float4*)(b + c0);
#pragma unroll
    for (int n = 0; n < 4; ++n) {
        acc[n][0] = bb.x; acc[n][1] = bb.y; acc[n][2] = bb.z; acc[n][3] = bb.w;
    }

    for (int k = 0; k < 128; k += 4) {
        float4 a4[4], x4[4];
#pragma unroll
        for (int n = 0; n < 4; ++n) {
            a4[n] = *(const float4*)&sM[nb + n][k];
            x4[n] = *(const float4*)&sX[nb + n][k];
        }
#pragma unroll
        for (int kk = 0; kk < 4; ++kk) {
            float4 wl = *(const float4*)(Wl + (k + kk) * 128 + c0);
            float4 wr = *(const float4*)(Wr + (k + kk) * 128 + c0);
#pragma unroll
            for (int n = 0; n < 4; ++n) {
                float a  = ((const float*)&a4[n])[kk];
                float xx = ((const float*)&x4[n])[kk];
                acc[n][0] += a * wl.x + xx * wr.x;
                acc[n][1] += a * wl.y + xx * wr.y;
                acc[n][2] += a * wl.z + xx * wr.z;
                acc[n][3] += a * wl.w + xx * wr.w;
            }
        }
    }

#pragma unroll
    for (int n = 0; n < 4; ++n) {
        int g = node0 + nb + n;
        if (g < n_nodes) {
            float4 o;
            o.x = fmaxf(acc[n][0], 0.f);
            o.y = fmaxf(acc[n][1], 0.f);
            o.z = fmaxf(acc[n][2], 0.f);
            o.w = fmaxf(acc[n][3], 0.f);
            *(float4*)(h + (size_t)g * 128 + c0) = o;
        }
    }
}

// ---------------------------------------------------------------------------
// Layer 2: out = mean2 @ W2l + h @ W2r + b2         [50k,128]x[128,64]
// ---------------------------------------------------------------------------

__global__ __launch_bounds__(256) void l2_kernel(
    const float* __restrict__ mean, const float* __restrict__ hfeat,
    const float* __restrict__ Wl, const float* __restrict__ Wr,
    const float* __restrict__ b, float* __restrict__ out, int n_nodes) {
    __shared__ float sM[32][128];
    __shared__ float sH[32][128];
    int tid = threadIdx.x;
    int node0 = blockIdx.x * 32;

    for (int i = tid; i < 32 * 32; i += 256) {
        int r = i >> 5;
        int c = (i & 31) << 2;
        int g = node0 + r;
        float4 mv = make_float4(0, 0, 0, 0), hv = make_float4(0, 0, 0, 0);
        if (g < n_nodes) {
            mv = *(const float4*)(mean + (size_t)g * 128 + c);
            hv = *(const float4*)(hfeat + (size_t)g * 128 + c);
        }
        *(float4*)&sM[r][c] = mv;
        *(float4*)&sH[r][c] = hv;
    }
    __syncthreads();

    int cg = tid & 15, ng = tid >> 4;
    int c0 = cg << 2, nb = ng << 1;
    float acc[2][4];
    float4 bb = *(const float4*)(b + c0);
#pragma unroll
    for (int n = 0; n < 2; ++n) {
        acc[n][0] = bb.x; acc[n][1] = bb.y; acc[n][2] = bb.z; acc[n][3] = bb.w;
    }

    for (int k = 0; k < 128; k += 4) {
        float4 a4[2], h4[2];
#pragma unroll
        for (int n = 0; n < 2; ++n) {
            a4[n] = *(const float4*)&sM[nb + n][k];
            h4[n] = *(const float4*)&sH[nb + n][k];
        }
#pragma unroll
        for (int kk = 0; kk < 4; ++kk) {
            float4 wl = *(const float4*)(Wl + (k + kk) * 64 + c0);
            float4 wr = *(const float4*)(Wr + (k + kk) * 64 + c0);
#pragma unroll
            for (int n = 0; n < 2; ++n) {
                float a  = ((const float*)&a4[n])[kk];
                float hh = ((const float*)&h4[n])[kk];
                acc[n][0] += a * wl.x + hh * wr.x;
                acc[n][1] += a * wl.y + hh * wr.y;
                acc[n][2] += a * wl.z + hh * wr.z;
                acc[n][3] += a * wl.w + hh * wr.w;
            }
        }
    }

#pragma unroll
    for (int n = 0; n < 2; ++n) {
        int g = node0 + nb + n;
        if (g < n_nodes) {
            float4 o;
            o.x = acc[n][0]; o.y = acc[n][1]; o.z = acc[n][2]; o.w = acc[n][3];
            *(float4*)(out + (size_t)g * 64 + c0) = o;
        }
    }
}

// ---------------------------------------------------------------------------

extern "C" void kernel_launch(void* const* d_in, const int* in_sizes, int n_in,
                              void* d_out, int out_size, void* d_ws, size_t ws_size,
                              hipStream_t stream) {
    const float* x   = (const float*)d_in[0];
    const int*   ei  = (const int*)d_in[1];
    const float* W1l = (const float*)d_in[2];
    const float* W1r = (const float*)d_in[3];
    const float* b1  = (const float*)d_in[4];
    const float* W2l = (const float*)d_in[5];
    const float* W2r = (const float*)d_in[6];
    const float* b2  = (const float*)d_in[7];
    float* out = (float*)d_out;

    int n_nodes = in_sizes[0] / IN_CH;
    int n_edges = in_sizes[1] / 2;
    int nsb = (n_nodes + SCAN_B - 1) / SCAN_B;   // scan blocks (196)

    // Workspace layout
    char* ws = (char*)d_ws;
    int* deg      = (int*)ws;                    // n_nodes
    int* offsets  = deg + n_nodes;               // n_nodes + 1
    int* cursor   = offsets + n_nodes + 1;       // n_nodes
    int* partials = cursor + n_nodes;            // nsb
    int* bases    = partials + nsb;              // nsb
    int* edge_src = bases + nsb;                 // n_edges
    size_t off = ((size_t)(3 * n_nodes + 1 + 2 * nsb + n_edges)) * sizeof(int);
    off = (off + 255) & ~(size_t)255;            // 256B align for float4
    float* mean = (float*)(ws + off);            // n_nodes * 128 (reused)
    float* h    = mean + (size_t)n_nodes * HID_CH;

    hipMemsetAsync(deg, 0, n_nodes * sizeof(int), stream);

    const int TB = 256;
    int eblocks = (n_edges + TB - 1) / TB;
    count_deg_kernel<<<eblocks, TB, 0, stream>>>(ei, deg, n_edges);
    scan_partials_kernel<<<nsb, SCAN_B, 0, stream>>>(deg, partials, n_nodes);
    scan_bases_kernel<<<1, 1024, 0, stream>>>(partials, bases, offsets, nsb, n_nodes);
    scan_final_kernel<<<nsb, SCAN_B, 0, stream>>>(deg, bases, offsets, cursor, n_nodes);
    fill_kernel<<<eblocks, TB, 0, stream>>>(ei, cursor, edge_src, n_edges);

    int gblocks = (n_nodes * 64 + TB - 1) / TB;  // one wave per node
    int mblocks = (n_nodes + 31) / 32;

    // Layer 1
    gather_mean_kernel<<<gblocks, TB, 0, stream>>>(x, offsets, edge_src, mean, n_nodes);
    l1_kernel<<<mblocks, 256, 0, stream>>>(mean, x, W1l, W1r, b1, h, n_nodes);

    // Layer 2 (reuse CSR and mean buffer)
    gather_mean_kernel<<<gblocks, TB, 0, stream>>>(h, offsets, edge_src, mean, n_nodes);
    l2_kernel<<<mblocks, 256, 0, stream>>>(mean, h, W2l, W2r, b2, out, n_nodes);
}

// Round 3
// 268.054 us; speedup vs baseline: 1.8980x; 1.4286x over previous
//
#include <hip/hip_runtime.h>
#include <hip/hip_bf16.h>

#define IN_CH 128
#define HID_CH 128
#define OUT_CH 64
#define SCAN_B 256

typedef __attribute__((ext_vector_type(8))) short bf16x8;
typedef __attribute__((ext_vector_type(4))) float f32x4;

__device__ __forceinline__ ushort f2bf(float f) {
    uint u = __float_as_uint(f);
    uint r = (u + 0x7fffu + ((u >> 16) & 1u)) >> 16;  // RNE
    return (ushort)r;
}

// ---------------------------------------------------------------------------
// CSR build: degree count -> 3-phase multi-block exclusive scan -> bucket fill
// ---------------------------------------------------------------------------

__global__ void count_deg_kernel(const int* __restrict__ ei, int* __restrict__ deg,
                                 int n_edges) {
    int e = blockIdx.x * blockDim.x + threadIdx.x;
    if (e < n_edges) {
        atomicAdd(&deg[ei[n_edges + e]], 1);  // row 1 = dst
    }
}

__global__ __launch_bounds__(SCAN_B) void scan_partials_kernel(
    const int* __restrict__ deg, int* __restrict__ partials, int n) {
    __shared__ int ws[SCAN_B / 64];
    int i = blockIdx.x * SCAN_B + threadIdx.x;
    int v = (i < n) ? deg[i] : 0;
    for (int off = 32; off > 0; off >>= 1) v += __shfl_down(v, off, 64);
    int lane = threadIdx.x & 63, w = threadIdx.x >> 6;
    if (lane == 0) ws[w] = v;
    __syncthreads();
    if (threadIdx.x == 0) {
        int s = 0;
        for (int k = 0; k < SCAN_B / 64; ++k) s += ws[k];
        partials[blockIdx.x] = s;
    }
}

__global__ __launch_bounds__(1024) void scan_bases_kernel(
    const int* __restrict__ partials, int* __restrict__ bases,
    int* __restrict__ offsets, int nblocks, int n) {
    __shared__ int sm[1024];
    int t = threadIdx.x;
    int v = (t < nblocks) ? partials[t] : 0;
    sm[t] = v;
    __syncthreads();
    for (int off = 1; off < 1024; off <<= 1) {
        int u = (t >= off) ? sm[t - off] : 0;
        __syncthreads();
        sm[t] += u;
        __syncthreads();
    }
    if (t < nblocks) bases[t] = sm[t] - v;
    if (t == 1023) offsets[n] = sm[1023];
}

__global__ __launch_bounds__(SCAN_B) void scan_final_kernel(
    const int* __restrict__ deg, const int* __restrict__ bases,
    int* __restrict__ offsets, int* __restrict__ cursor, int n) {
    __shared__ int sm[SCAN_B];
    int t = threadIdx.x;
    int i = blockIdx.x * SCAN_B + t;
    int v = (i < n) ? deg[i] : 0;
    sm[t] = v;
    __syncthreads();
    for (int off = 1; off < SCAN_B; off <<= 1) {
        int u = (t >= off) ? sm[t - off] : 0;
        __syncthreads();
        sm[t] += u;
        __syncthreads();
    }
    if (i < n) {
        int o = bases[blockIdx.x] + sm[t] - v;
        offsets[i] = o;
        cursor[i]  = o;
    }
}

__global__ void fill_kernel(const int* __restrict__ ei, int* __restrict__ cursor,
                            int* __restrict__ edge_src, int n_edges) {
    int e = blockIdx.x * blockDim.x + threadIdx.x;
    if (e < n_edges) {
        int s = ei[e];
        int d = ei[n_edges + e];
        int pos = atomicAdd(&cursor[d], 1);
        edge_src[pos] = s;
    }
}

// ---------------------------------------------------------------------------
// fp32 -> bf16 conversions / weight transpose
// ---------------------------------------------------------------------------

__global__ void cvt_f32_bf16_kernel(const float* __restrict__ in,
                                    ushort* __restrict__ out, int n) {
    int i = blockIdx.x * blockDim.x + threadIdx.x;
    if (i * 4 >= n) return;
    float4 v = *(const float4*)(in + i * 4);
    ushort4 o;
    o.x = f2bf(v.x); o.y = f2bf(v.y); o.z = f2bf(v.z); o.w = f2bf(v.w);
    *(ushort4*)(out + i * 4) = o;
}

// in: [K][N] f32 row-major  ->  out: [N][K] bf16 row-major (i.e. W^T)
__global__ void transpose_bf16_kernel(const float* __restrict__ in,
                                      ushort* __restrict__ out, int K, int N) {
    int idx = blockIdx.x * blockDim.x + threadIdx.x;
    if (idx >= K * N) return;
    int nn = idx / K, kk = idx % K;
    out[idx] = f2bf(in[kk * N + nn]);
}

// ---------------------------------------------------------------------------
// Gather-side mean over bf16 features: one wave per node; lane loads one dword
// (2 bf16 channels) -> a full 256B row per wave per edge. fp32 accumulate.
// ---------------------------------------------------------------------------

__global__ __launch_bounds__(256) void gather_mean_bf16_kernel(
    const ushort* __restrict__ feat, const int* __restrict__ offsets,
    const int* __restrict__ edge_src, ushort* __restrict__ mean, int n_nodes) {
    int wid  = (blockIdx.x * blockDim.x + threadIdx.x) >> 6;
    int lane = threadIdx.x & 63;
    if (wid >= n_nodes) return;
    int beg = offsets[wid];
    int end = offsets[wid + 1];
    float sx = 0.f, sy = 0.f;
    int e = beg;
    for (; e + 3 < end; e += 4) {
        uint a = *(const uint*)(feat + (size_t)edge_src[e]     * 128 + 2 * lane);
        uint b = *(const uint*)(feat + (size_t)edge_src[e + 1] * 128 + 2 * lane);
        uint c = *(const uint*)(feat + (size_t)edge_src[e + 2] * 128 + 2 * lane);
        uint d = *(const uint*)(feat + (size_t)edge_src[e + 3] * 128 + 2 * lane);
        sx += __uint_as_float(a << 16) + __uint_as_float(b << 16) +
              __uint_as_float(c << 16) + __uint_as_float(d << 16);
        sy += __uint_as_float(a & 0xffff0000u) + __uint_as_float(b & 0xffff0000u) +
              __uint_as_float(c & 0xffff0000u) + __uint_as_float(d & 0xffff0000u);
    }
    for (; e < end; ++e) {
        uint a = *(const uint*)(feat + (size_t)edge_src[e] * 128 + 2 * lane);
        sx += __uint_as_float(a << 16);
        sy += __uint_as_float(a & 0xffff0000u);
    }
    float inv = 1.0f / fmaxf((float)(end - beg), 1.0f);
    uint o = (uint)f2bf(sx * inv) | ((uint)f2bf(sy * inv) << 16);
    *(uint*)(mean + (size_t)wid * 128 + 2 * lane) = o;
}

// ---------------------------------------------------------------------------
// Layer 1 (MFMA): h = relu(mean @ W1l + x @ W1r + b1), bf16 in, bf16 out.
// Wave computes 32 rows x 128 cols. A frags direct from global (row-major,
// contiguous k); B frags from pre-transposed W^T [n][k] (contiguous k).
// ---------------------------------------------------------------------------

__global__ __launch_bounds__(256) void l1_mfma_kernel(
    const ushort* __restrict__ mean, const ushort* __restrict__ xb,
    const ushort* __restrict__ WlT, const ushort* __restrict__ WrT,
    const float* __restrict__ b, ushort* __restrict__ h, int n_nodes) {
    int wave = threadIdx.x >> 6, lane = threadIdx.x & 63;
    int m0 = (blockIdx.x * 4 + wave) * 32;
    int r  = lane & 15;
    int ko = (lane >> 4) * 8;

    int gc0 = min(m0 + r,      n_nodes - 1);
    int gc1 = min(m0 + 16 + r, n_nodes - 1);

    f32x4 acc[8][2] = {};
#pragma unroll
    for (int kk = 0; kk < 4; ++kk) {
        int kb = kk * 32 + ko;
        bf16x8 aM0 = *(const bf16x8*)(mean + (size_t)gc0 * 128 + kb);
        bf16x8 aM1 = *(const bf16x8*)(mean + (size_t)gc1 * 128 + kb);
        bf16x8 aX0 = *(const bf16x8*)(xb   + (size_t)gc0 * 128 + kb);
        bf16x8 aX1 = *(const bf16x8*)(xb   + (size_t)gc1 * 128 + kb);
#pragma unroll
        for (int j = 0; j < 8; ++j) {
            bf16x8 bL = *(const bf16x8*)(WlT + (size_t)(j * 16 + r) * 128 + kb);
            bf16x8 bR = *(const bf16x8*)(WrT + (size_t)(j * 16 + r) * 128 + kb);
            acc[j][0] = __builtin_amdgcn_mfma_f32_16x16x32_bf16(aM0, bL, acc[j][0], 0, 0, 0);
            acc[j][0] = __builtin_amdgcn_mfma_f32_16x16x32_bf16(aX0, bR, acc[j][0], 0, 0, 0);
            acc[j][1] = __builtin_amdgcn_mfma_f32_16x16x32_bf16(aM1, bL, acc[j][1], 0, 0, 0);
            acc[j][1] = __builtin_amdgcn_mfma_f32_16x16x32_bf16(aX1, bR, acc[j][1], 0, 0, 0);
        }
    }

#pragma unroll
    for (int j = 0; j < 8; ++j) {
        float bv = b[j * 16 + r];
#pragma unroll
        for (int s = 0; s < 2; ++s) {
            int rowbase = m0 + s * 16 + (lane >> 4) * 4;
#pragma unroll
            for (int q = 0; q < 4; ++q) {
                int g = rowbase + q;
                if (g < n_nodes)
                    h[(size_t)g * 128 + j * 16 + r] =
                        f2bf(fmaxf(acc[j][s][q] + bv, 0.f));
            }
        }
    }
}

// ---------------------------------------------------------------------------
// Layer 2 (MFMA): out = mean2 @ W2l + h @ W2r + b2, fp32 output [N,64].
// ---------------------------------------------------------------------------

__global__ __launch_bounds__(256) void l2_mfma_kernel(
    const ushort* __restrict__ mean, const ushort* __restrict__ hb,
    const ushort* __restrict__ WlT, const ushort* __restrict__ WrT,
    const float* __restrict__ b, float* __restrict__ out, int n_nodes) {
    int wave = threadIdx.x >> 6, lane = threadIdx.x & 63;
    int m0 = (blockIdx.x * 4 + wave) * 32;
    int r  = lane & 15;
    int ko = (lane >> 4) * 8;

    int gc0 = min(m0 + r,      n_nodes - 1);
    int gc1 = min(m0 + 16 + r, n_nodes - 1);

    f32x4 acc[4][2] = {};
#pragma unroll
    for (int kk = 0; kk < 4; ++kk) {
        int kb = kk * 32 + ko;
        bf16x8 aM0 = *(const bf16x8*)(mean + (size_t)gc0 * 128 + kb);
        bf16x8 aM1 = *(const bf16x8*)(mean + (size_t)gc1 * 128 + kb);
        bf16x8 aH0 = *(const bf16x8*)(hb   + (size_t)gc0 * 128 + kb);
        bf16x8 aH1 = *(const bf16x8*)(hb   + (size_t)gc1 * 128 + kb);
#pragma unroll
        for (int j = 0; j < 4; ++j) {
            bf16x8 bL = *(const bf16x8*)(WlT + (size_t)(j * 16 + r) * 128 + kb);
            bf16x8 bR = *(const bf16x8*)(WrT + (size_t)(j * 16 + r) * 128 + kb);
            acc[j][0] = __builtin_amdgcn_mfma_f32_16x16x32_bf16(aM0, bL, acc[j][0], 0, 0, 0);
            acc[j][0] = __builtin_amdgcn_mfma_f32_16x16x32_bf16(aH0, bR, acc[j][0], 0, 0, 0);
            acc[j][1] = __builtin_amdgcn_mfma_f32_16x16x32_bf16(aM1, bL, acc[j][1], 0, 0, 0);
            acc[j][1] = __builtin_amdgcn_mfma_f32_16x16x32_bf16(aH1, bR, acc[j][1], 0, 0, 0);
        }
    }

#pragma unroll
    for (int j = 0; j < 4; ++j) {
        float bv = b[j * 16 + r];
#pragma unroll
        for (int s = 0; s < 2; ++s) {
            int rowbase = m0 + s * 16 + (lane >> 4) * 4;
#pragma unroll
            for (int q = 0; q < 4; ++q) {
                int g = rowbase + q;
                if (g < n_nodes)
                    out[(size_t)g * 64 + j * 16 + r] = acc[j][s][q] + bv;
            }
        }
    }
}

// ---------------------------------------------------------------------------

extern "C" void kernel_launch(void* const* d_in, const int* in_sizes, int n_in,
                              void* d_out, int out_size, void* d_ws, size_t ws_size,
                              hipStream_t stream) {
    const float* x   = (const float*)d_in[0];
    const int*   ei  = (const int*)d_in[1];
    const float* W1l = (const float*)d_in[2];
    const float* W1r = (const float*)d_in[3];
    const float* b1  = (const float*)d_in[4];
    const float* W2l = (const float*)d_in[5];
    const float* W2r = (const float*)d_in[6];
    const float* b2  = (const float*)d_in[7];
    float* out = (float*)d_out;

    int n_nodes = in_sizes[0] / IN_CH;
    int n_edges = in_sizes[1] / 2;
    int nsb = (n_nodes + SCAN_B - 1) / SCAN_B;

    // Workspace layout
    char* ws = (char*)d_ws;
    int* deg      = (int*)ws;                    // n_nodes
    int* offsets  = deg + n_nodes;               // n_nodes + 1
    int* cursor   = offsets + n_nodes + 1;       // n_nodes
    int* partials = cursor + n_nodes;            // nsb
    int* bases    = partials + nsb;              // nsb
    int* edge_src = bases + nsb;                 // n_edges
    size_t off = ((size_t)(3 * n_nodes + 1 + 2 * nsb + n_edges)) * sizeof(int);
    off = (off + 255) & ~(size_t)255;
    ushort* xb    = (ushort*)(ws + off);             // n*128 bf16
    ushort* meanb = xb    + (size_t)n_nodes * 128;   // n*128 bf16
    ushort* hb    = meanb + (size_t)n_nodes * 128;   // n*128 bf16
    ushort* W1lT  = hb    + (size_t)n_nodes * 128;   // 128*128
    ushort* W1rT  = W1lT + 128 * 128;
    ushort* W2lT  = W1rT + 128 * 128;                // 64*128
    ushort* W2rT  = W2lT + 64 * 128;

    hipMemsetAsync(deg, 0, n_nodes * sizeof(int), stream);

    const int TB = 256;
    int eblocks = (n_edges + TB - 1) / TB;
    count_deg_kernel<<<eblocks, TB, 0, stream>>>(ei, deg, n_edges);
    scan_partials_kernel<<<nsb, SCAN_B, 0, stream>>>(deg, partials, n_nodes);
    scan_bases_kernel<<<1, 1024, 0, stream>>>(partials, bases, offsets, nsb, n_nodes);
    scan_final_kernel<<<nsb, SCAN_B, 0, stream>>>(deg, bases, offsets, cursor, n_nodes);
    fill_kernel<<<eblocks, TB, 0, stream>>>(ei, cursor, edge_src, n_edges);

    // Precision prep: x -> bf16, W -> W^T bf16
    int nx = n_nodes * IN_CH;
    cvt_f32_bf16_kernel<<<(nx / 4 + TB - 1) / TB, TB, 0, stream>>>(x, xb, nx);
    transpose_bf16_kernel<<<(128 * 128 + TB - 1) / TB, TB, 0, stream>>>(W1l, W1lT, 128, 128);
    transpose_bf16_kernel<<<(128 * 128 + TB - 1) / TB, TB, 0, stream>>>(W1r, W1rT, 128, 128);
    transpose_bf16_kernel<<<(128 * 64 + TB - 1) / TB, TB, 0, stream>>>(W2l, W2lT, 128, 64);
    transpose_bf16_kernel<<<(128 * 64 + TB - 1) / TB, TB, 0, stream>>>(W2r, W2rT, 128, 64);

    int gblocks = (n_nodes * 64 + TB - 1) / TB;      // one wave per node
    int mblocks = (n_nodes + 127) / 128;             // 4 waves x 32 rows per block

    // Layer 1
    gather_mean_bf16_kernel<<<gblocks, TB, 0, stream>>>(xb, offsets, edge_src, meanb, n_nodes);
    l1_mfma_kernel<<<mblocks, 256, 0, stream>>>(meanb, xb, W1lT, W1rT, b1, hb, n_nodes);

    // Layer 2
    gather_mean_bf16_kernel<<<gblocks, TB, 0, stream>>>(hb, offsets, edge_src, meanb, n_nodes);
    l2_mfma_kernel<<<mblocks, 256, 0, stream>>>(meanb, hb, W2lT, W2rT, b2, out, n_nodes);
}

// Round 7
// 248.036 us; speedup vs baseline: 2.0512x; 1.0807x over previous
//
#include <hip/hip_runtime.h>
#include <hip/hip_bf16.h>

#define IN_CH 128
#define HID_CH 128
#define OUT_CH 64
#define SCAN_B 256

typedef __attribute__((ext_vector_type(8))) short bf16x8;
typedef __attribute__((ext_vector_type(4))) float f32x4;

__device__ __forceinline__ ushort f2bf(float f) {
    uint u = __float_as_uint(f);
    uint r = (u + 0x7fffu + ((u >> 16) & 1u)) >> 16;  // RNE
    return (ushort)r;
}
__device__ __forceinline__ float bflo(uint u) { return __uint_as_float(u << 16); }
__device__ __forceinline__ float bfhi(uint u) { return __uint_as_float(u & 0xffff0000u); }

// ---------------------------------------------------------------------------
// Fused prep: [count_deg blocks] [x->bf16 blocks] [W transpose blocks]
// ---------------------------------------------------------------------------

__global__ __launch_bounds__(256) void prep_count_kernel(
    const int* __restrict__ ei, int* __restrict__ deg,
    const float* __restrict__ x, ushort* __restrict__ xb,
    const float* __restrict__ W1l, const float* __restrict__ W1r,
    const float* __restrict__ W2l, const float* __restrict__ W2r,
    ushort* __restrict__ W1lT, ushort* __restrict__ W1rT,
    ushort* __restrict__ W2lT, ushort* __restrict__ W2rT,
    int n_edges, int nx, int cnt_blocks, int cvt_blocks) {
    int b = blockIdx.x, tid = threadIdx.x;
    if (b < cnt_blocks) {
        int e4 = b * 256 + tid;
        if (e4 * 4 < n_edges) {
            int4 d = *(const int4*)(ei + n_edges + e4 * 4);  // dst row, 16B aligned
            atomicAdd(&deg[d.x], 1);
            atomicAdd(&deg[d.y], 1);
            atomicAdd(&deg[d.z], 1);
            atomicAdd(&deg[d.w], 1);
        }
    } else if (b < cnt_blocks + cvt_blocks) {
        int i = (b - cnt_blocks) * 256 + tid;
        if (i * 8 < nx) {
            float4 v0 = *(const float4*)(x + i * 8);
            float4 v1 = *(const float4*)(x + i * 8 + 4);
            uint4 o;
            o.x = (uint)f2bf(v0.x) | ((uint)f2bf(v0.y) << 16);
            o.y = (uint)f2bf(v0.z) | ((uint)f2bf(v0.w) << 16);
            o.z = (uint)f2bf(v1.x) | ((uint)f2bf(v1.y) << 16);
            o.w = (uint)f2bf(v1.z) | ((uint)f2bf(v1.w) << 16);
            *(uint4*)(xb + i * 8) = o;
        }
    } else {
        int t = (b - cnt_blocks - cvt_blocks) * 256 + tid;
        if (t < 16384) {                       // W1l^T  [128][128]
            int nn = t >> 7, kk = t & 127;
            W1lT[t] = f2bf(W1l[kk * 128 + nn]);
        } else if (t < 32768) {                // W1r^T
            int u = t - 16384;
            int nn = u >> 7, kk = u & 127;
            W1rT[u] = f2bf(W1r[kk * 128 + nn]);
        } else if (t < 40960) {                // W2l^T  [64][128]
            int u = t - 32768;
            int nn = u >> 7, kk = u & 127;
            W2lT[u] = f2bf(W2l[kk * 64 + nn]);
        } else if (t < 49152) {                // W2r^T
            int u = t - 40960;
            int nn = u >> 7, kk = u & 127;
            W2rT[u] = f2bf(W2r[kk * 64 + nn]);
        }
    }
}

// ---------------------------------------------------------------------------
// 3-phase exclusive scan of deg -> offsets & cursor
// ---------------------------------------------------------------------------

__global__ __launch_bounds__(SCAN_B) void scan_partials_kernel(
    const int* __restrict__ deg, int* __restrict__ partials, int n) {
    __shared__ int ws[SCAN_B / 64];
    int i = blockIdx.x * SCAN_B + threadIdx.x;
    int v = (i < n) ? deg[i] : 0;
    for (int off = 32; off > 0; off >>= 1) v += __shfl_down(v, off, 64);
    int lane = threadIdx.x & 63, w = threadIdx.x >> 6;
    if (lane == 0) ws[w] = v;
    __syncthreads();
    if (threadIdx.x == 0) {
        int s = 0;
        for (int k = 0; k < SCAN_B / 64; ++k) s += ws[k];
        partials[blockIdx.x] = s;
    }
}

__global__ __launch_bounds__(256) void scan_bases_kernel(
    const int* __restrict__ partials, int* __restrict__ bases,
    int* __restrict__ offsets, int nblocks, int n) {
    __shared__ int sm[256];
    int t = threadIdx.x;
    int v = (t < nblocks) ? partials[t] : 0;
    sm[t] = v;
    __syncthreads();
    for (int off = 1; off < 256; off <<= 1) {
        int u = (t >= off) ? sm[t - off] : 0;
        __syncthreads();
        sm[t] += u;
        __syncthreads();
    }
    if (t < nblocks) bases[t] = sm[t] - v;
    if (t == 255) offsets[n] = sm[255];
}

__global__ __launch_bounds__(SCAN_B) void scan_final_kernel(
    const int* __restrict__ deg, const int* __restrict__ bases,
    int* __restrict__ offsets, int* __restrict__ cursor, int n) {
    __shared__ int sm[SCAN_B];
    int t = threadIdx.x;
    int i = blockIdx.x * SCAN_B + t;
    int v = (i < n) ? deg[i] : 0;
    sm[t] = v;
    __syncthreads();
    for (int off = 1; off < SCAN_B; off <<= 1) {
        int u = (t >= off) ? sm[t - off] : 0;
        __syncthreads();
        sm[t] += u;
        __syncthreads();
    }
    if (i < n) {
        int o = bases[blockIdx.x] + sm[t] - v;
        offsets[i] = o;
        cursor[i]  = o;
    }
}

__global__ __launch_bounds__(256) void fill_kernel(
    const int* __restrict__ ei, int* __restrict__ cursor,
    int* __restrict__ edge_src, int n_edges) {
    int e4 = blockIdx.x * 256 + threadIdx.x;
    if (e4 * 4 >= n_edges) return;
    int4 s = *(const int4*)(ei + e4 * 4);
    int4 d = *(const int4*)(ei + n_edges + e4 * 4);
    edge_src[atomicAdd(&cursor[d.x], 1)] = s.x;
    edge_src[atomicAdd(&cursor[d.y], 1)] = s.y;
    edge_src[atomicAdd(&cursor[d.z], 1)] = s.z;
    edge_src[atomicAdd(&cursor[d.w], 1)] = s.w;
}

// ---------------------------------------------------------------------------
// Gather-side mean (bf16): one wave per node. dwordx4/lane, 16 lanes per row
// -> 4 edges per VMEM instruction, 8 edges in flight. Quarter-wave shfl_xor
// reduction at the end. fp32 accumulate.
// ---------------------------------------------------------------------------

__global__ __launch_bounds__(256) void gather_mean_bf16_kernel(
    const ushort* __restrict__ feat, const int* __restrict__ offsets,
    const int* __restrict__ edge_src, ushort* __restrict__ mean, int n_nodes) {
    int wid  = (blockIdx.x * blockDim.x + threadIdx.x) >> 6;
    int lane = threadIdx.x & 63;
    if (wid >= n_nodes) return;
    int beg = offsets[wid];
    int end = offsets[wid + 1];
    int q = lane >> 4;   // quarter: which edge of the quad
    int c = lane & 15;   // channel group: bf16 channels c*8 .. c*8+7
    float s0 = 0, s1 = 0, s2 = 0, s3 = 0, s4 = 0, s5 = 0, s6 = 0, s7 = 0;

    int e = beg;
    for (; e + 8 <= end; e += 8) {
        int r0 = edge_src[e + q];
        int r1 = edge_src[e + 4 + q];
        uint4 A = *(const uint4*)(feat + (size_t)r0 * 128 + c * 8);
        uint4 B = *(const uint4*)(feat + (size_t)r1 * 128 + c * 8);
        s0 += bflo(A.x) + bflo(B.x);  s1 += bfhi(A.x) + bfhi(B.x);
        s2 += bflo(A.y) + bflo(B.y);  s3 += bfhi(A.y) + bfhi(B.y);
        s4 += bflo(A.z) + bflo(B.z);  s5 += bfhi(A.z) + bfhi(B.z);
        s6 += bflo(A.w) + bflo(B.w);  s7 += bfhi(A.w) + bfhi(B.w);
    }
    int rem = end - e;
    if (rem > 0) {
        int i0 = min(e + q, end - 1);
        int i1 = min(e + 4 + q, end - 1);
        int r0 = edge_src[i0];
        int r1 = edge_src[i1];
        uint4 A = *(const uint4*)(feat + (size_t)r0 * 128 + c * 8);
        uint4 B = *(const uint4*)(feat + (size_t)r1 * 128 + c * 8);
        if (q < rem) {
            s0 += bflo(A.x);  s1 += bfhi(A.x);
            s2 += bflo(A.y);  s3 += bfhi(A.y);
            s4 += bflo(A.z);  s5 += bfhi(A.z);
            s6 += bflo(A.w);  s7 += bfhi(A.w);
        }
        if (4 + q < rem) {
            s0 += bflo(B.x);  s1 += bfhi(B.x);
            s2 += bflo(B.y);  s3 += bfhi(B.y);
            s4 += bflo(B.z);  s5 += bfhi(B.z);
            s6 += bflo(B.w);  s7 += bfhi(B.w);
        }
    }

    // combine the 4 quarter-wave partial sums (lanes c, c+16, c+32, c+48)
#pragma unroll
    for (int m = 16; m < 64; m <<= 1) {
        s0 += __shfl_xor(s0, m, 64);
        s1 += __shfl_xor(s1, m, 64);
        s2 += __shfl_xor(s2, m, 64);
        s3 += __shfl_xor(s3, m, 64);
        s4 += __shfl_xor(s4, m, 64);
        s5 += __shfl_xor(s5, m, 64);
        s6 += __shfl_xor(s6, m, 64);
        s7 += __shfl_xor(s7, m, 64);
    }

    if (q == 0) {
        float inv = 1.0f / fmaxf((float)(end - beg), 1.0f);
        uint4 o;
        o.x = (uint)f2bf(s0 * inv) | ((uint)f2bf(s1 * inv) << 16);
        o.y = (uint)f2bf(s2 * inv) | ((uint)f2bf(s3 * inv) << 16);
        o.z = (uint)f2bf(s4 * inv) | ((uint)f2bf(s5 * inv) << 16);
        o.w = (uint)f2bf(s6 * inv) | ((uint)f2bf(s7 * inv) << 16);
        *(uint4*)(mean + (size_t)wid * 128 + c * 8) = o;
    }
}

// ---------------------------------------------------------------------------
// Layer 1 (MFMA): h = relu(mean @ W1l + x @ W1r + b1), bf16 in, bf16 out.
// ---------------------------------------------------------------------------

__global__ __launch_bounds__(256) void l1_mfma_kernel(
    const ushort* __restrict__ mean, const ushort* __restrict__ xb,
    const ushort* __restrict__ WlT, const ushort* __restrict__ WrT,
    const float* __restrict__ b, ushort* __restrict__ h, int n_nodes) {
    int wave = threadIdx.x >> 6, lane = threadIdx.x & 63;
    int m0 = (blockIdx.x * 4 + wave) * 32;
    int r  = lane & 15;
    int ko = (lane >> 4) * 8;

    int gc0 = min(m0 + r,      n_nodes - 1);
    int gc1 = min(m0 + 16 + r, n_nodes - 1);

    f32x4 acc[8][2] = {};
#pragma unroll
    for (int kk = 0; kk < 4; ++kk) {
        int kb = kk * 32 + ko;
        bf16x8 aM0 = *(const bf16x8*)(mean + (size_t)gc0 * 128 + kb);
        bf16x8 aM1 = *(const bf16x8*)(mean + (size_t)gc1 * 128 + kb);
        bf16x8 aX0 = *(const bf16x8*)(xb   + (size_t)gc0 * 128 + kb);
        bf16x8 aX1 = *(const bf16x8*)(xb   + (size_t)gc1 * 128 + kb);
#pragma unroll
        for (int j = 0; j < 8; ++j) {
            bf16x8 bL = *(const bf16x8*)(WlT + (size_t)(j * 16 + r) * 128 + kb);
            bf16x8 bR = *(const bf16x8*)(WrT + (size_t)(j * 16 + r) * 128 + kb);
            acc[j][0] = __builtin_amdgcn_mfma_f32_16x16x32_bf16(aM0, bL, acc[j][0], 0, 0, 0);
            acc[j][0] = __builtin_amdgcn_mfma_f32_16x16x32_bf16(aX0, bR, acc[j][0], 0, 0, 0);
            acc[j][1] = __builtin_amdgcn_mfma_f32_16x16x32_bf16(aM1, bL, acc[j][1], 0, 0, 0);
            acc[j][1] = __builtin_amdgcn_mfma_f32_16x16x32_bf16(aX1, bR, acc[j][1], 0, 0, 0);
        }
    }

#pragma unroll
    for (int j = 0; j < 8; ++j) {
        float bv = b[j * 16 + r];
#pragma unroll
        for (int s = 0; s < 2; ++s) {
            int rowbase = m0 + s * 16 + (lane >> 4) * 4;
#pragma unroll
            for (int q = 0; q < 4; ++q) {
                int g = rowbase + q;
                if (g < n_nodes)
                    h[(size_t)g * 128 + j * 16 + r] =
                        f2bf(fmaxf(acc[j][s][q] + bv, 0.f));
            }
        }
    }
}

// ---------------------------------------------------------------------------
// Layer 2 (MFMA): out = mean2 @ W2l + h @ W2r + b2, fp32 output [N,64].
// ---------------------------------------------------------------------------

__global__ __launch_bounds__(256) void l2_mfma_kernel(
    const ushort* __restrict__ mean, const ushort* __restrict__ hb,
    const ushort* __restrict__ WlT, const ushort* __restrict__ WrT,
    const float* __restrict__ b, float* __restrict__ out, int n_nodes) {
    int wave = threadIdx.x >> 6, lane = threadIdx.x & 63;
    int m0 = (blockIdx.x * 4 + wave) * 32;
    int r  = lane & 15;
    int ko = (lane >> 4) * 8;

    int gc0 = min(m0 + r,      n_nodes - 1);
    int gc1 = min(m0 + 16 + r, n_nodes - 1);

    f32x4 acc[4][2] = {};
#pragma unroll
    for (int kk = 0; kk < 4; ++kk) {
        int kb = kk * 32 + ko;
        bf16x8 aM0 = *(const bf16x8*)(mean + (size_t)gc0 * 128 + kb);
        bf16x8 aM1 = *(const bf16x8*)(mean + (size_t)gc1 * 128 + kb);
        bf16x8 aH0 = *(const bf16x8*)(hb   + (size_t)gc0 * 128 + kb);
        bf16x8 aH1 = *(const bf16x8*)(hb   + (size_t)gc1 * 128 + kb);
#pragma unroll
        for (int j = 0; j < 4; ++j) {
            bf16x8 bL = *(const bf16x8*)(WlT + (size_t)(j * 16 + r) * 128 + kb);
            bf16x8 bR = *(const bf16x8*)(WrT + (size_t)(j * 16 + r) * 128 + kb);
            acc[j][0] = __builtin_amdgcn_mfma_f32_16x16x32_bf16(aM0, bL, acc[j][0], 0, 0, 0);
            acc[j][0] = __builtin_amdgcn_mfma_f32_16x16x32_bf16(aH0, bR, acc[j][0], 0, 0, 0);
            acc[j][1] = __builtin_amdgcn_mfma_f32_16x16x32_bf16(aM1, bL, acc[j][1], 0, 0, 0);
            acc[j][1] = __builtin_amdgcn_mfma_f32_16x16x32_bf16(aH1, bR, acc[j][1], 0, 0, 0);
        }
    }

#pragma unroll
    for (int j = 0; j < 4; ++j) {
        float bv = b[j * 16 + r];
#pragma unroll
        for (int s = 0; s < 2; ++s) {
            int rowbase = m0 + s * 16 + (lane >> 4) * 4;
#pragma unroll
            for (int q = 0; q < 4; ++q) {
                int g = rowbase + q;
                if (g < n_nodes)
                    out[(size_t)g * 64 + j * 16 + r] = acc[j][s][q] + bv;
            }
        }
    }
}

// ---------------------------------------------------------------------------

extern "C" void kernel_launch(void* const* d_in, const int* in_sizes, int n_in,
                              void* d_out, int out_size, void* d_ws, size_t ws_size,
                              hipStream_t stream) {
    const float* x   = (const float*)d_in[0];
    const int*   ei  = (const int*)d_in[1];
    const float* W1l = (const float*)d_in[2];
    const float* W1r = (const float*)d_in[3];
    const float* b1  = (const float*)d_in[4];
    const float* W2l = (const float*)d_in[5];
    const float* W2r = (const float*)d_in[6];
    const float* b2  = (const float*)d_in[7];
    float* out = (float*)d_out;

    int n_nodes = in_sizes[0] / IN_CH;
    int n_edges = in_sizes[1] / 2;
    int nsb = (n_nodes + SCAN_B - 1) / SCAN_B;

    // Workspace layout
    char* ws = (char*)d_ws;
    int* deg      = (int*)ws;                    // n_nodes
    int* offsets  = deg + n_nodes;               // n_nodes + 1
    int* cursor   = offsets + n_nodes + 1;       // n_nodes
    int* partials = cursor + n_nodes;            // nsb
    int* bases    = partials + nsb;              // nsb
    int* edge_src = bases + nsb;                 // n_edges
    size_t off = ((size_t)(3 * n_nodes + 1 + 2 * nsb + n_edges)) * sizeof(int);
    off = (off + 255) & ~(size_t)255;
    ushort* xb    = (ushort*)(ws + off);             // n*128 bf16
    ushort* meanb = xb    + (size_t)n_nodes * 128;   // n*128 bf16
    ushort* hb    = meanb + (size_t)n_nodes * 128;   // n*128 bf16
    ushort* W1lT  = hb    + (size_t)n_nodes * 128;   // 128*128
    ushort* W1rT  = W1lT + 128 * 128;
    ushort* W2lT  = W1rT + 128 * 128;                // 64*128
    ushort* W2rT  = W2lT + 64 * 128;

    hipMemsetAsync(deg, 0, n_nodes * sizeof(int), stream);

    const int TB = 256;
    int nx = n_nodes * IN_CH;
    int cnt_blocks = (n_edges / 4 + TB - 1) / TB;
    int cvt_blocks = (nx / 8 + TB - 1) / TB;
    int tr_blocks  = (49152 + TB - 1) / TB;

    prep_count_kernel<<<cnt_blocks + cvt_blocks + tr_blocks, TB, 0, stream>>>(
        ei, deg, x, xb, W1l, W1r, W2l, W2r, W1lT, W1rT, W2lT, W2rT,
        n_edges, nx, cnt_blocks, cvt_blocks);
    scan_partials_kernel<<<nsb, SCAN_B, 0, stream>>>(deg, partials, n_nodes);
    scan_bases_kernel<<<1, 256, 0, stream>>>(partials, bases, offsets, nsb, n_nodes);
    scan_final_kernel<<<nsb, SCAN_B, 0, stream>>>(deg, bases, offsets, cursor, n_nodes);
    fill_kernel<<<cnt_blocks, TB, 0, stream>>>(ei, cursor, edge_src, n_edges);

    int gblocks = (n_nodes * 64 + TB - 1) / TB;      // one wave per node
    int mblocks = (n_nodes + 127) / 128;             // 4 waves x 32 rows

    // Layer 1
    gather_mean_bf16_kernel<<<gblocks, TB, 0, stream>>>(xb, offsets, edge_src, meanb, n_nodes);
    l1_mfma_kernel<<<mblocks, 256, 0, stream>>>(meanb, xb, W1lT, W1rT, b1, hb, n_nodes);

    // Layer 2
    gather_mean_bf16_kernel<<<gblocks, TB, 0, stream>>>(hb, offsets, edge_src, meanb, n_nodes);
    l2_mfma_kernel<<<mblocks, 256, 0, stream>>>(meanb, hb, W2lT, W2rT, b2, out, n_nodes);
}